// Round 8
// baseline (34.769 us; speedup 1.0000x reference)
//
#include <hip/hip_runtime.h>

#define BB 4096
#define NN 64
#define DD 128
#define G  2
#define P2S 36   // part2 row stride (floats): 144B rows, 16B-aligned

// Fused, G=2 rows per block (2048 blocks, 256 threads) — R7 structure.
// Two generations of blocks per CU: gen-2 streams nbr while gen-1 runs its
// phase-2 tail, keeping HBM fed (tail-stagger hypothesis).
__global__ __launch_bounds__(256) void kFused(
    const float* __restrict__ stu,
    const float* __restrict__ conc,
    const float* __restrict__ nbr,
    const float* __restrict__ Ws,
    const float* __restrict__ bs,
    const float* __restrict__ Ww,
    float* __restrict__ y)
{
    const int t    = threadIdx.x;
    const int lane = t & 63;
    const int cg   = t & 31;        // float4 column group (cols cg*4..+3)
    const int g8   = t >> 5;        // half-wave group 0..7 (rows g8+8i)
    const int wv   = t >> 6;        // wave 0..3
    const int b0   = blockIdx.x * G;

    __shared__ __align__(16) float part2[NN * P2S];      // 9 KB logit partials
    __shared__ float wsm[NN];
    __shared__ float csum[G];
    __shared__ float maskh[G];
    __shared__ __align__(16) float u[G][2 * DD];         // 2 KB
    __shared__ __align__(16) float scratch[G * 8 * DD];  // 8 KB

    const float4 wb = reinterpret_cast<const float4*>(Ww + DD)[cg];  // Ww_b
    const float4* nb4 = reinterpret_cast<const float4*>(nbr);

    // ---- upfront: masks + u staging, one b-row per wave (waves 0..G-1) ----
    if (wv < G) {
        const int b = b0 + wv;
        float cv0 = conc[(size_t)b * DD + lane];
        float cv1 = conc[(size_t)b * DD + 64 + lane];
        float sv0 = stu [(size_t)b * DD + lane];
        float sv1 = stu [(size_t)b * DD + 64 + lane];
        u[wv][lane]           = 65.0f * sv0;
        u[wv][64 + lane]      = 65.0f * sv1;
        u[wv][DD + lane]      = 64.0f * cv0;
        u[wv][DD + 64 + lane] = 64.0f * cv1;
        float cs = cv0 + cv1, ss = sv0 + sv1;
#pragma unroll
        for (int o = 1; o < 64; o <<= 1) {
            cs += __shfl_xor(cs, o);
            ss += __shfl_xor(ss, o);
        }
        if (lane == 0) {
            csum[wv]  = cs;
            maskh[wv] = (ss != 0.0f) ? 0.5f : 0.0f;
        }
    }

    // ---- pre-load tile for g=0 ----
    float4 val[8], valn[8];
#pragma unroll
    for (int i = 0; i < 8; ++i)
        val[i] = nb4[(size_t)b0 * 2048 + t + 256 * i];

    for (int g = 0; g < G; ++g) {
        // ---- dot4 partials -> part2 (2-way LDS writes, free) ----
#pragma unroll
        for (int i = 0; i < 8; ++i) {
            const int row = g8 + 8 * i;
            part2[row * P2S + cg] =
                val[i].x * wb.x + val[i].y * wb.y + val[i].z * wb.z + val[i].w * wb.w;
        }
        // ---- prefetch g+1 tile (hides HBM latency under reduce/softmax) ----
        if (g < G - 1) {
#pragma unroll
            for (int i = 0; i < 8; ++i)
                valn[i] = nb4[(size_t)(b0 + g + 1) * 2048 + t + 256 * i];
        }
        __syncthreads();                    // B1: part2 ready (+ upfront csum)

        // ---- wave0: reduce 64 rows + softmax ----
        if (t < NN) {
            float s = 0.0f;
#pragma unroll
            for (int j = 0; j < 8; ++j) {
                const float4 p = *reinterpret_cast<const float4*>(&part2[t * P2S + j * 4]);
                s += p.x + p.y + p.z + p.w;
            }
            float m = s;
            m = fmaxf(m, __shfl_xor(m, 1));
            m = fmaxf(m, __shfl_xor(m, 2));
            m = fmaxf(m, __shfl_xor(m, 4));
            m = fmaxf(m, __shfl_xor(m, 8));
            m = fmaxf(m, __shfl_xor(m, 16));
            m = fmaxf(m, __shfl_xor(m, 32));
            float e = __expf(s - m);
            float den = e;
            den += __shfl_xor(den, 1);
            den += __shfl_xor(den, 2);
            den += __shfl_xor(den, 4);
            den += __shfl_xor(den, 8);
            den += __shfl_xor(den, 16);
            den += __shfl_xor(den, 32);
            wsm[t] = (csum[g] != 0.0f) ? (e / den) : (1.0f / 64.0f);
        }
        __syncthreads();                    // B2: wsm ready

        // ---- weighted sum in registers -> per-g scratch ----
        float4 a = {0.f, 0.f, 0.f, 0.f};
#pragma unroll
        for (int i = 0; i < 8; ++i) {
            const float w = wsm[g8 + 8 * i];    // LDS broadcast
            a.x += w * val[i].x; a.y += w * val[i].y;
            a.z += w * val[i].z; a.w += w * val[i].w;
        }
        reinterpret_cast<float4*>(scratch + g * 8 * DD)[g8 * 32 + cg] = a;

        if (g < G - 1) {
#pragma unroll
            for (int i = 0; i < 8; ++i) val[i] = valn[i];
        }
    }
    __syncthreads();                        // scratch + u staging visible

    // ---- fold weighted-sum partials into u (G*DD = 256 values) ----
    {
        const int gg = t >> 7;
        const int c  = t & 127;
        float s = 0.0f;
#pragma unroll
        for (int k = 0; k < 8; ++k) s += scratch[gg * 8 * DD + k * DD + c];
        u[gg][DD + c] += s;
    }
    __syncthreads();                        // u complete

    // ---- phase 2: y[b0+r] = maskh[r] * (u[r] @ Ws + 65*bs) ----
    float4 acc0 = {0,0,0,0}, acc1 = {0,0,0,0};
    const float4* Ws4 = reinterpret_cast<const float4*>(Ws);    // 256 x 32 float4
#pragma unroll 4
    for (int j = 0; j < 32; ++j) {
        const int k = g8 * 32 + j;
        float4 wq = Ws4[k * 32 + cg];       // coalesced, L2-resident
        float u0 = u[0][k], u1 = u[1][k];
        acc0.x += u0 * wq.x; acc0.y += u0 * wq.y; acc0.z += u0 * wq.z; acc0.w += u0 * wq.w;
        acc1.x += u1 * wq.x; acc1.y += u1 * wq.y; acc1.z += u1 * wq.z; acc1.w += u1 * wq.w;
    }
    {
        float4* pr = reinterpret_cast<float4*>(scratch);        // pr[g8][r][32]
        pr[(g8 * G + 0) * 32 + cg] = acc0;
        pr[(g8 * G + 1) * 32 + cg] = acc1;
    }
    __syncthreads();
    {
        const int r = t >> 7;               // 0/1
        const int c = t & 127;
        float s = 0.0f;
#pragma unroll
        for (int k2 = 0; k2 < 8; ++k2) s += scratch[(k2 * G + r) * DD + c];
        y[(size_t)(b0 + r) * DD + c] = (s + 65.0f * bs[c]) * maskh[r];
    }
}

extern "C" void kernel_launch(void* const* d_in, const int* in_sizes, int n_in,
                              void* d_out, int out_size, void* d_ws, size_t ws_size,
                              hipStream_t stream) {
    const float* stu  = (const float*)d_in[0];
    const float* conc = (const float*)d_in[1];
    const float* nbr  = (const float*)d_in[2];
    const float* Ws   = (const float*)d_in[3];
    const float* bs   = (const float*)d_in[4];
    const float* Ww   = (const float*)d_in[5];
    float* y = (float*)d_out;

    kFused<<<BB / G, 256, 0, stream>>>(stu, conc, nbr, Ws, bs, Ww, y);
}

// Round 9
// 31.963 us; speedup vs baseline: 1.0878x; 1.0878x over previous
//
#include <hip/hip_runtime.h>

#define BB 4096
#define NN 64
#define DD 128
#define G  8
#define P2S 36   // part2 row stride (floats): 144B rows, 16B-aligned

// Fused, G=8 rows per block (512 blocks, 256 threads) — R7/R8 structure,
// third point on the G-curve (G=2: 34.8, G=4: 29.9). Amortizes the measured
// ~1.2us/block G-independent overhead (phase-2 chain + barriers + upfront).
__global__ __launch_bounds__(256) void kFused(
    const float* __restrict__ stu,
    const float* __restrict__ conc,
    const float* __restrict__ nbr,
    const float* __restrict__ Ws,
    const float* __restrict__ bs,
    const float* __restrict__ Ww,
    float* __restrict__ y)
{
    const int t    = threadIdx.x;
    const int lane = t & 63;
    const int cg   = t & 31;        // float4 column group (cols cg*4..+3)
    const int g8   = t >> 5;        // half-wave group 0..7 (rows g8+8i)
    const int wv   = t >> 6;        // wave 0..3
    const int b0   = blockIdx.x * G;

    __shared__ __align__(16) float part2[NN * P2S];      // 9 KB logit partials
    __shared__ float wsm[NN];
    __shared__ float csum[G];
    __shared__ float maskh[G];
    __shared__ __align__(16) float u[G][2 * DD];         // 8 KB
    __shared__ __align__(16) float scratch[G * 8 * DD];  // 32 KB

    const float4 wb = reinterpret_cast<const float4*>(Ww + DD)[cg];  // Ww_b
    const float4* nb4 = reinterpret_cast<const float4*>(nbr);

    // ---- upfront: masks + u staging, 2 b-rows per wave ----
#pragma unroll
    for (int rr = wv; rr < G; rr += 4) {
        const int b = b0 + rr;
        float cv0 = conc[(size_t)b * DD + lane];
        float cv1 = conc[(size_t)b * DD + 64 + lane];
        float sv0 = stu [(size_t)b * DD + lane];
        float sv1 = stu [(size_t)b * DD + 64 + lane];
        u[rr][lane]           = 65.0f * sv0;
        u[rr][64 + lane]      = 65.0f * sv1;
        u[rr][DD + lane]      = 64.0f * cv0;
        u[rr][DD + 64 + lane] = 64.0f * cv1;
        float cs = cv0 + cv1, ss = sv0 + sv1;
#pragma unroll
        for (int o = 1; o < 64; o <<= 1) {
            cs += __shfl_xor(cs, o);
            ss += __shfl_xor(ss, o);
        }
        if (lane == 0) {
            csum[rr]  = cs;
            maskh[rr] = (ss != 0.0f) ? 0.5f : 0.0f;
        }
    }

    // ---- pre-load tile for g=0 ----
    float4 val[8], valn[8];
#pragma unroll
    for (int i = 0; i < 8; ++i)
        val[i] = nb4[(size_t)b0 * 2048 + t + 256 * i];

    for (int g = 0; g < G; ++g) {
        // ---- dot4 partials -> part2 (2-way LDS writes, free) ----
#pragma unroll
        for (int i = 0; i < 8; ++i) {
            const int row = g8 + 8 * i;
            part2[row * P2S + cg] =
                val[i].x * wb.x + val[i].y * wb.y + val[i].z * wb.z + val[i].w * wb.w;
        }
        // ---- prefetch g+1 tile (hides HBM latency under reduce/softmax) ----
        if (g < G - 1) {
#pragma unroll
            for (int i = 0; i < 8; ++i)
                valn[i] = nb4[(size_t)(b0 + g + 1) * 2048 + t + 256 * i];
        }
        __syncthreads();                    // B1: part2 ready (+ upfront csum)

        // ---- wave0: reduce 64 rows + softmax ----
        if (t < NN) {
            float s = 0.0f;
#pragma unroll
            for (int j = 0; j < 8; ++j) {
                const float4 p = *reinterpret_cast<const float4*>(&part2[t * P2S + j * 4]);
                s += p.x + p.y + p.z + p.w;
            }
            float m = s;
            m = fmaxf(m, __shfl_xor(m, 1));
            m = fmaxf(m, __shfl_xor(m, 2));
            m = fmaxf(m, __shfl_xor(m, 4));
            m = fmaxf(m, __shfl_xor(m, 8));
            m = fmaxf(m, __shfl_xor(m, 16));
            m = fmaxf(m, __shfl_xor(m, 32));
            float e = __expf(s - m);
            float den = e;
            den += __shfl_xor(den, 1);
            den += __shfl_xor(den, 2);
            den += __shfl_xor(den, 4);
            den += __shfl_xor(den, 8);
            den += __shfl_xor(den, 16);
            den += __shfl_xor(den, 32);
            wsm[t] = (csum[g] != 0.0f) ? (e / den) : (1.0f / 64.0f);
        }
        __syncthreads();                    // B2: wsm ready

        // ---- weighted sum in registers -> per-g scratch ----
        float4 a = {0.f, 0.f, 0.f, 0.f};
#pragma unroll
        for (int i = 0; i < 8; ++i) {
            const float w = wsm[g8 + 8 * i];    // LDS broadcast
            a.x += w * val[i].x; a.y += w * val[i].y;
            a.z += w * val[i].z; a.w += w * val[i].w;
        }
        reinterpret_cast<float4*>(scratch + g * 8 * DD)[g8 * 32 + cg] = a;

        if (g < G - 1) {
#pragma unroll
            for (int i = 0; i < 8; ++i) val[i] = valn[i];
        }
    }
    __syncthreads();                        // scratch + u staging visible

    // ---- fold weighted-sum partials into u (G*DD = 1024 values) ----
#pragma unroll
    for (int it = 0; it < G * DD / 256; ++it) {
        const int idx = t + 256 * it;
        const int gg  = idx >> 7;
        const int c   = idx & 127;
        float s = 0.0f;
#pragma unroll
        for (int k = 0; k < 8; ++k) s += scratch[gg * 8 * DD + k * DD + c];
        u[gg][DD + c] += s;
    }
    __syncthreads();                        // u complete

    // ---- phase 2: y[b0+r] = maskh[r] * (u[r] @ Ws + 65*bs) ----
    float4 acc[G];
#pragma unroll
    for (int r = 0; r < G; ++r) acc[r] = {0.f, 0.f, 0.f, 0.f};
    const float4* Ws4 = reinterpret_cast<const float4*>(Ws);    // 256 x 32 float4
#pragma unroll 4
    for (int j = 0; j < 32; ++j) {
        const int k = g8 * 32 + j;
        float4 wq = Ws4[k * 32 + cg];       // coalesced, L2-resident
#pragma unroll
        for (int r = 0; r < G; ++r) {
            const float ur = u[r][k];
            acc[r].x += ur * wq.x; acc[r].y += ur * wq.y;
            acc[r].z += ur * wq.z; acc[r].w += ur * wq.w;
        }
    }
    {
        float4* pr = reinterpret_cast<float4*>(scratch);        // pr[g8][r][32]
#pragma unroll
        for (int r = 0; r < G; ++r)
            pr[(g8 * G + r) * 32 + cg] = acc[r];
    }
    __syncthreads();
#pragma unroll
    for (int i = 0; i < G * DD / 256; ++i) {
        const int idx = t + 256 * i;
        const int r = idx >> 7;
        const int c = idx & 127;
        float s = 0.0f;
#pragma unroll
        for (int k2 = 0; k2 < 8; ++k2) s += scratch[(k2 * G + r) * DD + c];
        y[(size_t)(b0 + r) * DD + c] = (s + 65.0f * bs[c]) * maskh[r];
    }
}

extern "C" void kernel_launch(void* const* d_in, const int* in_sizes, int n_in,
                              void* d_out, int out_size, void* d_ws, size_t ws_size,
                              hipStream_t stream) {
    const float* stu  = (const float*)d_in[0];
    const float* conc = (const float*)d_in[1];
    const float* nbr  = (const float*)d_in[2];
    const float* Ws   = (const float*)d_in[3];
    const float* bs   = (const float*)d_in[4];
    const float* Ww   = (const float*)d_in[5];
    float* y = (float*)d_out;

    kFused<<<BB / G, 256, 0, stream>>>(stu, conc, nbr, Ws, bs, Ww, y);
}